// Round 10
// baseline (491.047 us; speedup 1.0000x reference)
//
#include <hip/hip_runtime.h>

#define NDF 96            // feature dim
#define NCHB 12           // u16x8 (8-feat, 16B) chunks per bf16 feature row (96/8)
#define BSH 8             // 256 nodes per dst-bucket
#define BCAP 8192         // entries per bucket (u32 bucket slab & padded csr slab)
#define TILE 4096         // edges per passA block

typedef unsigned short u16x8 __attribute__((ext_vector_type(8)));

__device__ __forceinline__ float bf2f(unsigned short u) {
    union { unsigned int i; float f; } x;
    x.i = ((unsigned int)u) << 16;
    return x.f;
}
__device__ __forceinline__ unsigned short f2bf(float f) {
    union { float f; unsigned int i; } x;
    x.f = f;
    unsigned int i = x.i;
    return (unsigned short)((i + 0x7FFFu + ((i >> 16) & 1u)) >> 16);  // RNE
}

// ---------------- init: zero bucket/bin counters + sentinel rows ----------------
// Sentinel row n of hsA/hsB stays zero all call (padding gathers land there).
__global__ void k_binit(int* __restrict__ bcount, int* __restrict__ binc,
                        unsigned short* __restrict__ hsA,
                        unsigned short* __restrict__ hsB, int n) {
    int t = threadIdx.x;
    bcount[t] = 0;
    if (t < 8) binc[t] = 0;
    u16x8 z = {0, 0, 0, 0, 0, 0, 0, 0};
    if (t < NCHB)            ((u16x8*)hsA)[(size_t)n * NCHB + t]          = z;
    else if (t < 2 * NCHB)   ((u16x8*)hsB)[(size_t)n * NCHB + (t - NCHB)] = z;
}

// Pass A: partition random edges into dst-buckets of 256 nodes. Per block:
// LDS histogram -> LDS scan -> global per-bucket reservation -> LDS staging
// in bucket-grouped order -> coalesced write of (dst<<16|src) u32 entries.
__global__ void __launch_bounds__(512) k_passA(
        const int* __restrict__ src, const int* __restrict__ dst, int nr,
        int* __restrict__ bcount, unsigned int* __restrict__ bucket) {
    __shared__ unsigned int stage[TILE];
    __shared__ int cnt[256], sstart[256], lcur[256], gbase[256];
    __shared__ int wsum4[4], pref4[4];
    int tid  = threadIdx.x;
    int tile = blockIdx.x * TILE;
    int cnt_e = min(TILE, nr - tile);
    if (tid < 256) cnt[tid] = 0;
    __syncthreads();
    for (int k = tid; k < cnt_e; k += 512)
        atomicAdd(&cnt[dst[tile + k] >> BSH], 1);
    __syncthreads();
    int x = 0, val = 0;
    if (tid < 256) {                  // 256-wide scan: 4 wave-scans + combine
        x = cnt[tid];
        val = x;
        int lane = tid & 63;
        #pragma unroll
        for (int off = 1; off < 64; off <<= 1) {
            int t = __shfl_up(val, off, 64);
            if (lane >= off) val += t;
        }
        if (lane == 63) wsum4[tid >> 6] = val;
    }
    __syncthreads();
    if (tid == 0) {
        int s = 0;
        #pragma unroll
        for (int w = 0; w < 4; ++w) { pref4[w] = s; s += wsum4[w]; }
    }
    __syncthreads();
    if (tid < 256) {
        sstart[tid] = val + pref4[tid >> 6] - x;    // exclusive block-local start
        lcur[tid]   = 0;
        gbase[tid]  = (x > 0) ? atomicAdd(&bcount[tid], x) : 0;
    }
    __syncthreads();
    for (int k = tid; k < cnt_e; k += 512) {
        int d = dst[tile + k];
        int s = src[tile + k];
        int b = d >> BSH;
        int pos = atomicAdd(&lcur[b], 1);
        stage[sstart[b] + pos] = ((unsigned int)d << 16) | (unsigned int)s;
    }
    __syncthreads();
    for (int k = tid; k < cnt_e; k += 512) {        // coalesced write-out
        unsigned int u = stage[k];
        int b = (int)(u >> 24);                     // dst>>8
        bucket[((size_t)b << 13) + gbase[b] + (k - sstart[b])] = u;
    }
}

// Pass BC (fused): per bucket — degree count, padded-length scan, LDS-staged
// CSR fill with sentinel padding, coalesced write-out, feature scaling
// (hs0 = bf16(F*d^-1/2), hinit = bf16(F*d^-1)), and degree-bin rank assignment
// for the prop-side node permutation.
__global__ void __launch_bounds__(512) k_passBC(
        const int* __restrict__ bcount, const unsigned int* __restrict__ bucket,
        const float* __restrict__ feat, int* __restrict__ rdeg_g,
        int* __restrict__ row_ptr, unsigned short* __restrict__ csr,
        unsigned short* __restrict__ hs, unsigned short* __restrict__ hinit,
        int* __restrict__ binc, unsigned int* __restrict__ nbrk,
        int n) {
    __shared__ int dl[256], cur[256];
    __shared__ int wsum4[4], pref4[4];
    __shared__ int total_s;
    __shared__ unsigned short stg[BCAP];
    int tid = threadIdx.x;
    int b   = blockIdx.x;
    if (tid < 256) dl[tid] = 0;
    __syncthreads();
    int cb = bcount[b];
    const unsigned int* __restrict__ bp = bucket + ((size_t)b << 13);
    for (int k = tid; k < cb; k += 512)
        atomicAdd(&dl[(bp[k] >> 16) & 255], 1);
    __syncthreads();
    int x = 0, val = 0;
    if (tid < 256) {                  // scan of 8-padded lengths
        x = (dl[tid] + 7) & ~7;
        val = x;
        int lane = tid & 63;
        #pragma unroll
        for (int off = 1; off < 64; off <<= 1) {
            int t = __shfl_up(val, off, 64);
            if (lane >= off) val += t;
        }
        if (lane == 63) wsum4[tid >> 6] = val;
    }
    __syncthreads();
    if (tid == 0) {
        int s = 0;
        #pragma unroll
        for (int w = 0; w < 4; ++w) { pref4[w] = s; s += wsum4[w]; }
        total_s = s;
    }
    __syncthreads();
    if (tid < 256) {
        int off_ex = val + pref4[tid >> 6] - x;     // padded exclusive offset
        cur[tid] = off_ex;
        int node = (b << BSH) + tid;
        if (node < n) {
            rdeg_g[node]  = dl[tid];
            row_ptr[node] = (b << 13) + off_ex;
            int bin  = min((dl[tid] + 7) >> 3, 7);  // iteration-count bin
            int rank = atomicAdd(&binc[bin], 1);
            nbrk[node] = ((unsigned int)rank << 3) | (unsigned int)bin;
        }
    }
    __syncthreads();
    int total = total_s;
    for (int k = tid; k < total; k += 512)          // sentinel padding
        stg[k] = (unsigned short)n;
    __syncthreads();
    for (int k = tid; k < cb; k += 512) {           // LDS scatter
        unsigned int u = bp[k];
        int p = atomicAdd(&cur[(u >> 16) & 255], 1);
        stg[p] = (unsigned short)(u & 0xFFFFu);
    }
    __syncthreads();
    unsigned short* __restrict__ cout = csr + ((size_t)b << 13);
    for (int k = tid; k < total; k += 512)          // coalesced write-out
        cout[k] = stg[k];
    // fused feature scaling for this bucket's nodes (dl stable since count)
    const float4* __restrict__ f4 = (const float4*)feat;
    for (int k = tid; k < 256 * NCHB; k += 512) {
        int lv = k / NCHB;
        int c  = k - lv * NCHB;
        int v  = (b << BSH) + lv;
        if (v >= n) break;                          // k monotonic per thread
        float d  = (float)(dl[lv] + 1);
        float s  = rsqrtf(d);
        float iv = 1.0f / d;
        int ci = v * NCHB + c;
        float4 fa = f4[(size_t)ci * 2];
        float4 fb = f4[(size_t)ci * 2 + 1];
        u16x8 o, oi;
        o[0] = f2bf(fa.x * s);  oi[0] = f2bf(fa.x * iv);
        o[1] = f2bf(fa.y * s);  oi[1] = f2bf(fa.y * iv);
        o[2] = f2bf(fa.z * s);  oi[2] = f2bf(fa.z * iv);
        o[3] = f2bf(fa.w * s);  oi[3] = f2bf(fa.w * iv);
        o[4] = f2bf(fb.x * s);  oi[4] = f2bf(fb.x * iv);
        o[5] = f2bf(fb.y * s);  oi[5] = f2bf(fb.y * iv);
        o[6] = f2bf(fb.z * s);  oi[6] = f2bf(fb.z * iv);
        o[7] = f2bf(fb.w * s);  oi[7] = f2bf(fb.w * iv);
        ((u16x8*)hs)[ci]    = o;
        ((u16x8*)hinit)[ci] = oi;
    }
}

// Build the degree-binned permutation: perm[base(bin)+rank] = node.
// Bin bases derived by each thread from the 8 global bin counters (LDS copy).
__global__ void k_perm(const unsigned int* __restrict__ nbrk,
                       const int* __restrict__ binc,
                       int* __restrict__ perm, int n) {
    __shared__ int bl[8];
    int tid = threadIdx.x;
    if (tid < 8) bl[tid] = binc[tid];
    __syncthreads();
    int i = blockIdx.x * blockDim.x + tid;
    if (i < n) {
        unsigned int p = nbrk[i];
        int bin  = (int)(p & 7u);
        int rank = (int)(p >> 3);
        int base = 0;
        #pragma unroll
        for (int b = 0; b < 7; ++b) base += (b < bin) ? bl[b] : 0;
        perm[base + rank] = i;
    }
}

// ---------------- propagation ----------------
// Thread = (slot g, chunk c); node v = perm[g] — nodes grouped by iteration
// count so each wave's gather loop is near-uniform (kills max-of-6 divergence).
// Rows 8-padded & sentinel-filled: uniform 8-block inner loop, one 16B u16x8
// csr load per 8 gathers. Accumulator seeded with own row (self-loop).
//   h_new = (own + sum hs[s]) * ds + hinit[v],  ds = rsqrt(rdeg+1)
//   LAST=0: write bf16(h_new * ds);  LAST=1: write fp32 h_new.
template <int LAST>
__global__ void __launch_bounds__(256) k_prop(
        const unsigned short* __restrict__ hs, const int* __restrict__ row_ptr,
        const int* __restrict__ rdeg, const unsigned short* __restrict__ csr,
        const unsigned short* __restrict__ hinit, const int* __restrict__ perm,
        void* __restrict__ outp, int nt) {
    int t = blockIdx.x * blockDim.x + threadIdx.x;
    if (t >= nt) return;
    int g = t / NCHB;
    int c = t - g * NCHB;
    int v = perm[g];                            // broadcast across 12 lanes
    int beg = row_ptr[v];                       // multiple of 8
    int dv  = rdeg[v];
    int nit = (dv + 7) >> 3;                    // 8-blocks (padded)
    const u16x8* __restrict__ hs8  = (const u16x8*)hs;
    const u16x8* __restrict__ csr8 = (const u16x8*)csr + (beg >> 3);
    int ci = v * NCHB + c;
    u16x8 own = hs8[ci];                        // self-loop contribution
    float a0 = bf2f(own[0]), a1 = bf2f(own[1]);
    float a2 = bf2f(own[2]), a3 = bf2f(own[3]);
    float a4 = bf2f(own[4]), a5 = bf2f(own[5]);
    float a6 = bf2f(own[6]), a7 = bf2f(own[7]);

    #define ACC(HV) do { \
        a0 += bf2f((HV)[0]); a1 += bf2f((HV)[1]); \
        a2 += bf2f((HV)[2]); a3 += bf2f((HV)[3]); \
        a4 += bf2f((HV)[4]); a5 += bf2f((HV)[5]); \
        a6 += bf2f((HV)[6]); a7 += bf2f((HV)[7]); } while (0)

    for (int it = 0; it < nit; ++it) {
        u16x8 sv8 = csr8[it];                   // 8 neighbor indices, 1 load
        u16x8 h0 = hs8[(int)sv8[0] * NCHB + c];
        u16x8 h1 = hs8[(int)sv8[1] * NCHB + c];
        u16x8 h2 = hs8[(int)sv8[2] * NCHB + c];
        u16x8 h3 = hs8[(int)sv8[3] * NCHB + c];
        u16x8 h4 = hs8[(int)sv8[4] * NCHB + c];
        u16x8 h5 = hs8[(int)sv8[5] * NCHB + c];
        u16x8 h6 = hs8[(int)sv8[6] * NCHB + c];
        u16x8 h7 = hs8[(int)sv8[7] * NCHB + c];
        ACC(h0); ACC(h1); ACC(h2); ACC(h3);
        ACC(h4); ACC(h5); ACC(h6); ACC(h7);
    }
    #undef ACC

    float sv = rsqrtf((float)(dv + 1));
    u16x8 hi = ((const u16x8*)hinit)[ci];
    float r0 = a0 * sv + bf2f(hi[0]);
    float r1 = a1 * sv + bf2f(hi[1]);
    float r2 = a2 * sv + bf2f(hi[2]);
    float r3 = a3 * sv + bf2f(hi[3]);
    float r4 = a4 * sv + bf2f(hi[4]);
    float r5 = a5 * sv + bf2f(hi[5]);
    float r6 = a6 * sv + bf2f(hi[6]);
    float r7 = a7 * sv + bf2f(hi[7]);
    if (LAST) {
        float4* o4 = (float4*)outp;
        o4[(size_t)ci * 2]     = make_float4(r0, r1, r2, r3);
        o4[(size_t)ci * 2 + 1] = make_float4(r4, r5, r6, r7);
    } else {
        u16x8 o;
        o[0] = f2bf(r0 * sv); o[1] = f2bf(r1 * sv);
        o[2] = f2bf(r2 * sv); o[3] = f2bf(r3 * sv);
        o[4] = f2bf(r4 * sv); o[5] = f2bf(r5 * sv);
        o[6] = f2bf(r6 * sv); o[7] = f2bf(r7 * sv);
        ((u16x8*)outp)[ci] = o;
    }
}

// ---------------- launch ----------------

extern "C" void kernel_launch(void* const* d_in, const int* in_sizes, int n_in,
                              void* d_out, int out_size, void* d_ws, size_t ws_size,
                              hipStream_t stream) {
    const int*   src  = (const int*)d_in[0];
    const int*   dst  = (const int*)d_in[1];
    const float* feat = (const float*)d_in[2];
    const int E  = in_sizes[0];
    const int n  = in_sizes[2] / NDF;
    const int nr = E - n;              // random edges; appended self-loops implicit
    float* out = (float*)d_out;

    // workspace carve-up (256B aligned)
    char* p = (char*)d_ws;
    auto take = [&](size_t bytes) {
        char* r = p;
        p += (bytes + 255) & ~size_t(255);
        return r;
    };
    const int NBK = (n + 255) >> 8;    // dst-buckets of 256 nodes
    int* bcount          = (int*)take(256 * 4);
    int* binc            = (int*)take(8 * 4);
    int* row_ptr         = (int*)take((size_t)n * 4);
    int* rdeg            = (int*)take((size_t)n * 4);
    int* perm            = (int*)take((size_t)n * 4);
    unsigned int* nbrk   = (unsigned int*)take((size_t)n * 4);
    unsigned int* bucket = (unsigned int*)take((size_t)256 * BCAP * 4);
    unsigned short* csr  = (unsigned short*)take((size_t)256 * BCAP * 2);
    unsigned short* hsA   = (unsigned short*)take((size_t)(n + 1) * NDF * 2);
    unsigned short* hsB   = (unsigned short*)take((size_t)(n + 1) * NDF * 2);
    unsigned short* hinit = (unsigned short*)take((size_t)n * NDF * 2);
    (void)ws_size;

    const int nt = n * NCHB;
    const int bT = (nt + 255) / 256;
    const int bN = (n + 255) / 256;
    const int bA = (nr + TILE - 1) / TILE;

    // build (4 launches): init -> bucket partition -> fused count/fill/scale
    // -> degree-binned permutation
    k_binit <<<1, 256, 0, stream>>>(bcount, binc, hsA, hsB, n);
    k_passA <<<bA, 512, 0, stream>>>(src, dst, nr, bcount, bucket);
    k_passBC<<<NBK, 512, 0, stream>>>(bcount, bucket, feat, rdeg, row_ptr,
                                      csr, hsA, hinit, binc, nbrk, n);
    k_perm  <<<bN, 256, 0, stream>>>(nbrk, binc, perm, n);

    // K = 3 propagation rounds (ping-pong hsA/hsB, final round writes d_out)
    k_prop<0><<<bT, 256, 0, stream>>>(hsA, row_ptr, rdeg, csr, hinit, perm, hsB, nt);
    k_prop<0><<<bT, 256, 0, stream>>>(hsB, row_ptr, rdeg, csr, hinit, perm, hsA, nt);
    k_prop<1><<<bT, 256, 0, stream>>>(hsA, row_ptr, rdeg, csr, hinit, perm, out, nt);
}

// Round 11
// 117.884 us; speedup vs baseline: 4.1655x; 4.1655x over previous
//
#include <hip/hip_runtime.h>

#define NDF 96            // feature dim
#define NCHB 12           // u16x8 (8-feat, 16B) chunks per bf16 feature row (96/8)
#define BSH 8             // 256 nodes per dst-bucket
#define BCAP 8192         // entries per bucket (u32 bucket slab & padded csr slab)
#define TILE 4096         // edges per passA block

typedef unsigned short u16x8 __attribute__((ext_vector_type(8)));

__device__ __forceinline__ float bf2f(unsigned short u) {
    union { unsigned int i; float f; } x;
    x.i = ((unsigned int)u) << 16;
    return x.f;
}
__device__ __forceinline__ unsigned short f2bf(float f) {
    union { float f; unsigned int i; } x;
    x.f = f;
    unsigned int i = x.i;
    return (unsigned short)((i + 0x7FFFu + ((i >> 16) & 1u)) >> 16);  // RNE
}

// ---------------- init: zero bucket/bin counters + sentinel rows ----------------
// Sentinel row n of hsA/hsB stays zero all call (padding gathers land there).
__global__ void k_binit(int* __restrict__ bcount, int* __restrict__ binc,
                        unsigned short* __restrict__ hsA,
                        unsigned short* __restrict__ hsB, int n) {
    int t = threadIdx.x;
    bcount[t] = 0;
    if (t < 8) binc[t] = 0;
    u16x8 z = {0, 0, 0, 0, 0, 0, 0, 0};
    if (t < NCHB)            ((u16x8*)hsA)[(size_t)n * NCHB + t]          = z;
    else if (t < 2 * NCHB)   ((u16x8*)hsB)[(size_t)n * NCHB + (t - NCHB)] = z;
}

// Pass A: partition random edges into dst-buckets of 256 nodes. Per block:
// LDS histogram -> LDS scan -> global per-bucket reservation -> LDS staging
// in bucket-grouped order -> coalesced write of (dst<<16|src) u32 entries.
__global__ void __launch_bounds__(512) k_passA(
        const int* __restrict__ src, const int* __restrict__ dst, int nr,
        int* __restrict__ bcount, unsigned int* __restrict__ bucket) {
    __shared__ unsigned int stage[TILE];
    __shared__ int cnt[256], sstart[256], lcur[256], gbase[256];
    __shared__ int wsum4[4], pref4[4];
    int tid  = threadIdx.x;
    int tile = blockIdx.x * TILE;
    int cnt_e = min(TILE, nr - tile);
    if (tid < 256) cnt[tid] = 0;
    __syncthreads();
    for (int k = tid; k < cnt_e; k += 512)
        atomicAdd(&cnt[dst[tile + k] >> BSH], 1);
    __syncthreads();
    int x = 0, val = 0;
    if (tid < 256) {                  // 256-wide scan: 4 wave-scans + combine
        x = cnt[tid];
        val = x;
        int lane = tid & 63;
        #pragma unroll
        for (int off = 1; off < 64; off <<= 1) {
            int t = __shfl_up(val, off, 64);
            if (lane >= off) val += t;
        }
        if (lane == 63) wsum4[tid >> 6] = val;
    }
    __syncthreads();
    if (tid == 0) {
        int s = 0;
        #pragma unroll
        for (int w = 0; w < 4; ++w) { pref4[w] = s; s += wsum4[w]; }
    }
    __syncthreads();
    if (tid < 256) {
        sstart[tid] = val + pref4[tid >> 6] - x;    // exclusive block-local start
        lcur[tid]   = 0;
        gbase[tid]  = (x > 0) ? atomicAdd(&bcount[tid], x) : 0;
    }
    __syncthreads();
    for (int k = tid; k < cnt_e; k += 512) {
        int d = dst[tile + k];
        int s = src[tile + k];
        int b = d >> BSH;
        int pos = atomicAdd(&lcur[b], 1);
        stage[sstart[b] + pos] = ((unsigned int)d << 16) | (unsigned int)s;
    }
    __syncthreads();
    for (int k = tid; k < cnt_e; k += 512) {        // coalesced write-out
        unsigned int u = stage[k];
        int b = (int)(u >> 24);                     // dst>>8
        bucket[((size_t)b << 13) + gbase[b] + (k - sstart[b])] = u;
    }
}

// Pass BC (fused): per bucket — degree count, padded-length scan, LDS-staged
// CSR fill with sentinel padding, coalesced write-out, feature scaling
// (hs0 = bf16(F*d^-1/2), hinit = bf16(F*d^-1)), and degree-bin slot assignment
// via LDS-aggregated histogram (ONE global atomic per bucket per bin — the
// per-node global atomic in the previous round serialized 50K ops on 8
// addresses and cost ~380us).
__global__ void __launch_bounds__(512) k_passBC(
        const int* __restrict__ bcount, const unsigned int* __restrict__ bucket,
        const float* __restrict__ feat, int* __restrict__ rdeg_g,
        int* __restrict__ row_ptr, unsigned short* __restrict__ csr,
        unsigned short* __restrict__ hs, unsigned short* __restrict__ hinit,
        int* __restrict__ binc, unsigned int* __restrict__ nbrk,
        int n) {
    __shared__ int dl[256], cur[256];
    __shared__ int wsum4[4], pref4[4];
    __shared__ int binc_l[8], gbase8[8];
    __shared__ int total_s;
    __shared__ unsigned short stg[BCAP];
    int tid = threadIdx.x;
    int b   = blockIdx.x;
    if (tid < 256) dl[tid] = 0;
    if (tid < 8) binc_l[tid] = 0;
    __syncthreads();
    int cb = bcount[b];
    const unsigned int* __restrict__ bp = bucket + ((size_t)b << 13);
    for (int k = tid; k < cb; k += 512)
        atomicAdd(&dl[(bp[k] >> 16) & 255], 1);
    __syncthreads();
    int x = 0, val = 0;
    if (tid < 256) {                  // scan of 8-padded lengths
        x = (dl[tid] + 7) & ~7;
        val = x;
        int lane = tid & 63;
        #pragma unroll
        for (int off = 1; off < 64; off <<= 1) {
            int t = __shfl_up(val, off, 64);
            if (lane >= off) val += t;
        }
        if (lane == 63) wsum4[tid >> 6] = val;
    }
    __syncthreads();
    if (tid == 0) {
        int s = 0;
        #pragma unroll
        for (int w = 0; w < 4; ++w) { pref4[w] = s; s += wsum4[w]; }
        total_s = s;
    }
    __syncthreads();
    int node = (b << BSH) + tid;
    int bin = 0, lrank = 0;
    bool live = (tid < 256) && (node < n);
    if (tid < 256) {
        int off_ex = val + pref4[tid >> 6] - x;     // padded exclusive offset
        cur[tid] = off_ex;
        if (live) {
            rdeg_g[node]  = dl[tid];
            row_ptr[node] = (b << 13) + off_ex;
            bin   = min((dl[tid] + 7) >> 3, 7);     // iteration-count bin
            lrank = atomicAdd(&binc_l[bin], 1);     // LDS: intra-bucket rank
        }
    }
    __syncthreads();
    if (tid < 8)                                     // 8 global atomics/bucket
        gbase8[tid] = (binc_l[tid] > 0) ? atomicAdd(&binc[tid], binc_l[tid]) : 0;
    __syncthreads();
    if (live)
        nbrk[node] = ((unsigned int)(gbase8[bin] + lrank) << 3) | (unsigned int)bin;
    int total = total_s;
    for (int k = tid; k < total; k += 512)          // sentinel padding
        stg[k] = (unsigned short)n;
    __syncthreads();
    for (int k = tid; k < cb; k += 512) {           // LDS scatter
        unsigned int u = bp[k];
        int p = atomicAdd(&cur[(u >> 16) & 255], 1);
        stg[p] = (unsigned short)(u & 0xFFFFu);
    }
    __syncthreads();
    unsigned short* __restrict__ cout = csr + ((size_t)b << 13);
    for (int k = tid; k < total; k += 512)          // coalesced write-out
        cout[k] = stg[k];
    // fused feature scaling for this bucket's nodes (dl stable since count)
    const float4* __restrict__ f4 = (const float4*)feat;
    for (int k = tid; k < 256 * NCHB; k += 512) {
        int lv = k / NCHB;
        int c  = k - lv * NCHB;
        int v  = (b << BSH) + lv;
        if (v >= n) break;                          // k monotonic per thread
        float d  = (float)(dl[lv] + 1);
        float s  = rsqrtf(d);
        float iv = 1.0f / d;
        int ci = v * NCHB + c;
        float4 fa = f4[(size_t)ci * 2];
        float4 fb = f4[(size_t)ci * 2 + 1];
        u16x8 o, oi;
        o[0] = f2bf(fa.x * s);  oi[0] = f2bf(fa.x * iv);
        o[1] = f2bf(fa.y * s);  oi[1] = f2bf(fa.y * iv);
        o[2] = f2bf(fa.z * s);  oi[2] = f2bf(fa.z * iv);
        o[3] = f2bf(fa.w * s);  oi[3] = f2bf(fa.w * iv);
        o[4] = f2bf(fb.x * s);  oi[4] = f2bf(fb.x * iv);
        o[5] = f2bf(fb.y * s);  oi[5] = f2bf(fb.y * iv);
        o[6] = f2bf(fb.z * s);  oi[6] = f2bf(fb.z * iv);
        o[7] = f2bf(fb.w * s);  oi[7] = f2bf(fb.w * iv);
        ((u16x8*)hs)[ci]    = o;
        ((u16x8*)hinit)[ci] = oi;
    }
}

// Build the degree-binned permutation: perm[base(bin)+slot] = node.
// nbrk already holds the node's global slot within its bin; bases derived
// from the 8 final bin counters.
__global__ void k_perm(const unsigned int* __restrict__ nbrk,
                       const int* __restrict__ binc,
                       int* __restrict__ perm, int n) {
    __shared__ int bl[8];
    int tid = threadIdx.x;
    if (tid < 8) bl[tid] = binc[tid];
    __syncthreads();
    int i = blockIdx.x * blockDim.x + tid;
    if (i < n) {
        unsigned int p = nbrk[i];
        int bin  = (int)(p & 7u);
        int slot = (int)(p >> 3);
        int base = 0;
        #pragma unroll
        for (int b = 0; b < 7; ++b) base += (b < bin) ? bl[b] : 0;
        perm[base + slot] = i;
    }
}

// ---------------- propagation ----------------
// Thread = (slot g, chunk c); node v = perm[g] — nodes grouped by iteration
// count so each wave's gather loop is near-uniform (kills max-of-6 divergence).
// Rows 8-padded & sentinel-filled: uniform 8-block inner loop, one 16B u16x8
// csr load per 8 gathers. Accumulator seeded with own row (self-loop).
//   h_new = (own + sum hs[s]) * ds + hinit[v],  ds = rsqrt(rdeg+1)
//   LAST=0: write bf16(h_new * ds);  LAST=1: write fp32 h_new.
template <int LAST>
__global__ void __launch_bounds__(256) k_prop(
        const unsigned short* __restrict__ hs, const int* __restrict__ row_ptr,
        const int* __restrict__ rdeg, const unsigned short* __restrict__ csr,
        const unsigned short* __restrict__ hinit, const int* __restrict__ perm,
        void* __restrict__ outp, int nt) {
    int t = blockIdx.x * blockDim.x + threadIdx.x;
    if (t >= nt) return;
    int g = t / NCHB;
    int c = t - g * NCHB;
    int v = perm[g];                            // broadcast across 12 lanes
    int beg = row_ptr[v];                       // multiple of 8
    int dv  = rdeg[v];
    int nit = (dv + 7) >> 3;                    // 8-blocks (padded)
    const u16x8* __restrict__ hs8  = (const u16x8*)hs;
    const u16x8* __restrict__ csr8 = (const u16x8*)csr + (beg >> 3);
    int ci = v * NCHB + c;
    u16x8 own = hs8[ci];                        // self-loop contribution
    float a0 = bf2f(own[0]), a1 = bf2f(own[1]);
    float a2 = bf2f(own[2]), a3 = bf2f(own[3]);
    float a4 = bf2f(own[4]), a5 = bf2f(own[5]);
    float a6 = bf2f(own[6]), a7 = bf2f(own[7]);

    #define ACC(HV) do { \
        a0 += bf2f((HV)[0]); a1 += bf2f((HV)[1]); \
        a2 += bf2f((HV)[2]); a3 += bf2f((HV)[3]); \
        a4 += bf2f((HV)[4]); a5 += bf2f((HV)[5]); \
        a6 += bf2f((HV)[6]); a7 += bf2f((HV)[7]); } while (0)

    for (int it = 0; it < nit; ++it) {
        u16x8 sv8 = csr8[it];                   // 8 neighbor indices, 1 load
        u16x8 h0 = hs8[(int)sv8[0] * NCHB + c];
        u16x8 h1 = hs8[(int)sv8[1] * NCHB + c];
        u16x8 h2 = hs8[(int)sv8[2] * NCHB + c];
        u16x8 h3 = hs8[(int)sv8[3] * NCHB + c];
        u16x8 h4 = hs8[(int)sv8[4] * NCHB + c];
        u16x8 h5 = hs8[(int)sv8[5] * NCHB + c];
        u16x8 h6 = hs8[(int)sv8[6] * NCHB + c];
        u16x8 h7 = hs8[(int)sv8[7] * NCHB + c];
        ACC(h0); ACC(h1); ACC(h2); ACC(h3);
        ACC(h4); ACC(h5); ACC(h6); ACC(h7);
    }
    #undef ACC

    float sv = rsqrtf((float)(dv + 1));
    u16x8 hi = ((const u16x8*)hinit)[ci];
    float r0 = a0 * sv + bf2f(hi[0]);
    float r1 = a1 * sv + bf2f(hi[1]);
    float r2 = a2 * sv + bf2f(hi[2]);
    float r3 = a3 * sv + bf2f(hi[3]);
    float r4 = a4 * sv + bf2f(hi[4]);
    float r5 = a5 * sv + bf2f(hi[5]);
    float r6 = a6 * sv + bf2f(hi[6]);
    float r7 = a7 * sv + bf2f(hi[7]);
    if (LAST) {
        float4* o4 = (float4*)outp;
        o4[(size_t)ci * 2]     = make_float4(r0, r1, r2, r3);
        o4[(size_t)ci * 2 + 1] = make_float4(r4, r5, r6, r7);
    } else {
        u16x8 o;
        o[0] = f2bf(r0 * sv); o[1] = f2bf(r1 * sv);
        o[2] = f2bf(r2 * sv); o[3] = f2bf(r3 * sv);
        o[4] = f2bf(r4 * sv); o[5] = f2bf(r5 * sv);
        o[6] = f2bf(r6 * sv); o[7] = f2bf(r7 * sv);
        ((u16x8*)outp)[ci] = o;
    }
}

// ---------------- launch ----------------

extern "C" void kernel_launch(void* const* d_in, const int* in_sizes, int n_in,
                              void* d_out, int out_size, void* d_ws, size_t ws_size,
                              hipStream_t stream) {
    const int*   src  = (const int*)d_in[0];
    const int*   dst  = (const int*)d_in[1];
    const float* feat = (const float*)d_in[2];
    const int E  = in_sizes[0];
    const int n  = in_sizes[2] / NDF;
    const int nr = E - n;              // random edges; appended self-loops implicit
    float* out = (float*)d_out;

    // workspace carve-up (256B aligned)
    char* p = (char*)d_ws;
    auto take = [&](size_t bytes) {
        char* r = p;
        p += (bytes + 255) & ~size_t(255);
        return r;
    };
    const int NBK = (n + 255) >> 8;    // dst-buckets of 256 nodes
    int* bcount          = (int*)take(256 * 4);
    int* binc            = (int*)take(8 * 4);
    int* row_ptr         = (int*)take((size_t)n * 4);
    int* rdeg            = (int*)take((size_t)n * 4);
    int* perm            = (int*)take((size_t)n * 4);
    unsigned int* nbrk   = (unsigned int*)take((size_t)n * 4);
    unsigned int* bucket = (unsigned int*)take((size_t)256 * BCAP * 4);
    unsigned short* csr  = (unsigned short*)take((size_t)256 * BCAP * 2);
    unsigned short* hsA   = (unsigned short*)take((size_t)(n + 1) * NDF * 2);
    unsigned short* hsB   = (unsigned short*)take((size_t)(n + 1) * NDF * 2);
    unsigned short* hinit = (unsigned short*)take((size_t)n * NDF * 2);
    (void)ws_size;

    const int nt = n * NCHB;
    const int bT = (nt + 255) / 256;
    const int bN = (n + 255) / 256;
    const int bA = (nr + TILE - 1) / TILE;

    // build (4 launches): init -> bucket partition -> fused count/fill/scale
    // -> degree-binned permutation
    k_binit <<<1, 256, 0, stream>>>(bcount, binc, hsA, hsB, n);
    k_passA <<<bA, 512, 0, stream>>>(src, dst, nr, bcount, bucket);
    k_passBC<<<NBK, 512, 0, stream>>>(bcount, bucket, feat, rdeg, row_ptr,
                                      csr, hsA, hinit, binc, nbrk, n);
    k_perm  <<<bN, 256, 0, stream>>>(nbrk, binc, perm, n);

    // K = 3 propagation rounds (ping-pong hsA/hsB, final round writes d_out)
    k_prop<0><<<bT, 256, 0, stream>>>(hsA, row_ptr, rdeg, csr, hinit, perm, hsB, nt);
    k_prop<0><<<bT, 256, 0, stream>>>(hsB, row_ptr, rdeg, csr, hinit, perm, hsA, nt);
    k_prop<1><<<bT, 256, 0, stream>>>(hsA, row_ptr, rdeg, csr, hinit, perm, out, nt);
}

// Round 12
// 105.949 us; speedup vs baseline: 4.6348x; 1.1127x over previous
//
#include <hip/hip_runtime.h>

#define NDF 96            // feature dim
#define NCHB 12           // u16x8 (8-feat, 16B) chunks per bf16 feature row (96/8)
#define BSH 8             // 256 nodes per dst-bucket
#define BCAP 8192         // entries per bucket (u32 bucket slab & padded csr slab)
#define TILE 4096         // edges per passA block

typedef unsigned short u16x8 __attribute__((ext_vector_type(8)));

__device__ __forceinline__ float bf2f(unsigned short u) {
    union { unsigned int i; float f; } x;
    x.i = ((unsigned int)u) << 16;
    return x.f;
}
__device__ __forceinline__ unsigned short f2bf(float f) {
    union { float f; unsigned int i; } x;
    x.f = f;
    unsigned int i = x.i;
    return (unsigned short)((i + 0x7FFFu + ((i >> 16) & 1u)) >> 16);  // RNE
}

// ---------------- init: zero bucket counters + sentinel rows ----------------
// Sentinel row n of hs0/hsB/hsC stays zero all call (padding gathers land there).
__global__ void k_binit(int* __restrict__ bcount, unsigned short* __restrict__ hs0,
                        unsigned short* __restrict__ hsB,
                        unsigned short* __restrict__ hsC, int n) {
    int t = threadIdx.x;
    bcount[t] = 0;
    u16x8 z = {0, 0, 0, 0, 0, 0, 0, 0};
    if (t < NCHB)            ((u16x8*)hs0)[(size_t)n * NCHB + t]              = z;
    else if (t < 2 * NCHB)   ((u16x8*)hsB)[(size_t)n * NCHB + (t - NCHB)]     = z;
    else if (t < 3 * NCHB)   ((u16x8*)hsC)[(size_t)n * NCHB + (t - 2 * NCHB)] = z;
}

// Pass A: partition random edges into dst-buckets of 256 nodes. Per block:
// LDS histogram -> LDS scan -> global per-bucket reservation -> LDS staging
// in bucket-grouped order -> coalesced write of (dst<<16|src) u32 entries.
__global__ void __launch_bounds__(512) k_passA(
        const int* __restrict__ src, const int* __restrict__ dst, int nr,
        int* __restrict__ bcount, unsigned int* __restrict__ bucket) {
    __shared__ unsigned int stage[TILE];
    __shared__ int cnt[256], sstart[256], lcur[256], gbase[256];
    __shared__ int wsum4[4], pref4[4];
    int tid  = threadIdx.x;
    int tile = blockIdx.x * TILE;
    int cnt_e = min(TILE, nr - tile);
    if (tid < 256) cnt[tid] = 0;
    __syncthreads();
    for (int k = tid; k < cnt_e; k += 512)
        atomicAdd(&cnt[dst[tile + k] >> BSH], 1);
    __syncthreads();
    int x = 0, val = 0;
    if (tid < 256) {                  // 256-wide scan: 4 wave-scans + combine
        x = cnt[tid];
        val = x;
        int lane = tid & 63;
        #pragma unroll
        for (int off = 1; off < 64; off <<= 1) {
            int t = __shfl_up(val, off, 64);
            if (lane >= off) val += t;
        }
        if (lane == 63) wsum4[tid >> 6] = val;
    }
    __syncthreads();
    if (tid == 0) {
        int s = 0;
        #pragma unroll
        for (int w = 0; w < 4; ++w) { pref4[w] = s; s += wsum4[w]; }
    }
    __syncthreads();
    if (tid < 256) {
        sstart[tid] = val + pref4[tid >> 6] - x;    // exclusive block-local start
        lcur[tid]   = 0;
        gbase[tid]  = (x > 0) ? atomicAdd(&bcount[tid], x) : 0;
    }
    __syncthreads();
    for (int k = tid; k < cnt_e; k += 512) {
        int d = dst[tile + k];
        int s = src[tile + k];
        int b = d >> BSH;
        int pos = atomicAdd(&lcur[b], 1);
        stage[sstart[b] + pos] = ((unsigned int)d << 16) | (unsigned int)s;
    }
    __syncthreads();
    for (int k = tid; k < cnt_e; k += 512) {        // coalesced write-out
        unsigned int u = stage[k];
        int b = (int)(u >> 24);                     // dst>>8
        bucket[((size_t)b << 13) + gbase[b] + (k - sstart[b])] = u;
    }
}

// Pass BC (fused): per bucket — degree count, padded-length scan, LDS-staged
// CSR fill with sentinel padding, coalesced write-out, and feature scaling
// hs0 = bf16(F * d^{-1/2}). (hinit buffer eliminated: hinit = hs0 * d^{-1/2},
// computed on the fly in the props.)
__global__ void __launch_bounds__(512) k_passBC(
        const int* __restrict__ bcount, const unsigned int* __restrict__ bucket,
        const float* __restrict__ feat, int* __restrict__ rdeg_g,
        int* __restrict__ row_ptr, unsigned short* __restrict__ csr,
        unsigned short* __restrict__ hs0, int n) {
    __shared__ int dl[256], cur[256];
    __shared__ int wsum4[4], pref4[4];
    __shared__ int total_s;
    __shared__ unsigned short stg[BCAP];
    int tid = threadIdx.x;
    int b   = blockIdx.x;
    if (tid < 256) dl[tid] = 0;
    __syncthreads();
    int cb = bcount[b];
    const unsigned int* __restrict__ bp = bucket + ((size_t)b << 13);
    for (int k = tid; k < cb; k += 512)
        atomicAdd(&dl[(bp[k] >> 16) & 255], 1);
    __syncthreads();
    int x = 0, val = 0;
    if (tid < 256) {                  // scan of 8-padded lengths
        x = (dl[tid] + 7) & ~7;
        val = x;
        int lane = tid & 63;
        #pragma unroll
        for (int off = 1; off < 64; off <<= 1) {
            int t = __shfl_up(val, off, 64);
            if (lane >= off) val += t;
        }
        if (lane == 63) wsum4[tid >> 6] = val;
    }
    __syncthreads();
    if (tid == 0) {
        int s = 0;
        #pragma unroll
        for (int w = 0; w < 4; ++w) { pref4[w] = s; s += wsum4[w]; }
        total_s = s;
    }
    __syncthreads();
    if (tid < 256) {
        int off_ex = val + pref4[tid >> 6] - x;     // padded exclusive offset
        cur[tid] = off_ex;
        int node = (b << BSH) + tid;
        if (node < n) {
            rdeg_g[node]  = dl[tid];
            row_ptr[node] = (b << 13) + off_ex;
        }
    }
    __syncthreads();
    int total = total_s;
    for (int k = tid; k < total; k += 512)          // sentinel padding
        stg[k] = (unsigned short)n;
    __syncthreads();
    for (int k = tid; k < cb; k += 512) {           // LDS scatter
        unsigned int u = bp[k];
        int p = atomicAdd(&cur[(u >> 16) & 255], 1);
        stg[p] = (unsigned short)(u & 0xFFFFu);
    }
    __syncthreads();
    unsigned short* __restrict__ cout = csr + ((size_t)b << 13);
    for (int k = tid; k < total; k += 512)          // coalesced write-out
        cout[k] = stg[k];
    // fused feature scaling for this bucket's nodes (dl stable since count)
    const float4* __restrict__ f4 = (const float4*)feat;
    for (int k = tid; k < 256 * NCHB; k += 512) {
        int lv = k / NCHB;
        int c  = k - lv * NCHB;
        int v  = (b << BSH) + lv;
        if (v >= n) break;                          // k monotonic per thread
        float s = rsqrtf((float)(dl[lv] + 1));
        int ci = v * NCHB + c;
        float4 fa = f4[(size_t)ci * 2];
        float4 fb = f4[(size_t)ci * 2 + 1];
        u16x8 o;
        o[0] = f2bf(fa.x * s);
        o[1] = f2bf(fa.y * s);
        o[2] = f2bf(fa.z * s);
        o[3] = f2bf(fa.w * s);
        o[4] = f2bf(fb.x * s);
        o[5] = f2bf(fb.y * s);
        o[6] = f2bf(fb.z * s);
        o[7] = f2bf(fb.w * s);
        ((u16x8*)hs0)[ci] = o;
    }
}

// ---------------- propagation ----------------
// Thread = (node v, chunk c), sequential (perm experiment removed: net loss).
// Rows 8-padded & sentinel-filled: uniform 8-block inner loop, one 16B u16x8
// csr load per 8 gathers. Accumulator seeded with own row (self-loop).
//   h_new = (acc + hs0[v]) * ds,   ds = rsqrt(rdeg+1)
//     (since hinit = hs0*ds and acc*ds + hs0*ds = (acc+hs0)*ds)
//   FIRST=1: hs==hs0, so the init term reuses the in-register own row.
//   LAST=0: write bf16(h_new * ds);  LAST=1: write fp32 h_new.
template <int FIRST, int LAST>
__global__ void __launch_bounds__(256) k_prop(
        const unsigned short* __restrict__ hs, const unsigned short* __restrict__ hs0,
        const int* __restrict__ row_ptr, const int* __restrict__ rdeg,
        const unsigned short* __restrict__ csr,
        void* __restrict__ outp, int nt) {
    int t = blockIdx.x * blockDim.x + threadIdx.x;
    if (t >= nt) return;
    int v = t / NCHB;
    int c = t - v * NCHB;
    int beg = row_ptr[v];                       // multiple of 8
    int dv  = rdeg[v];
    int nit = (dv + 7) >> 3;                    // 8-blocks (padded)
    const u16x8* __restrict__ hs8  = (const u16x8*)hs;
    const u16x8* __restrict__ csr8 = (const u16x8*)csr + (beg >> 3);
    u16x8 own = hs8[t];                         // self-loop contribution
    float a0 = bf2f(own[0]), a1 = bf2f(own[1]);
    float a2 = bf2f(own[2]), a3 = bf2f(own[3]);
    float a4 = bf2f(own[4]), a5 = bf2f(own[5]);
    float a6 = bf2f(own[6]), a7 = bf2f(own[7]);

    #define ACC(HV) do { \
        a0 += bf2f((HV)[0]); a1 += bf2f((HV)[1]); \
        a2 += bf2f((HV)[2]); a3 += bf2f((HV)[3]); \
        a4 += bf2f((HV)[4]); a5 += bf2f((HV)[5]); \
        a6 += bf2f((HV)[6]); a7 += bf2f((HV)[7]); } while (0)

    for (int it = 0; it < nit; ++it) {
        u16x8 sv8 = csr8[it];                   // 8 neighbor indices, 1 load
        u16x8 h0 = hs8[(int)sv8[0] * NCHB + c];
        u16x8 h1 = hs8[(int)sv8[1] * NCHB + c];
        u16x8 h2 = hs8[(int)sv8[2] * NCHB + c];
        u16x8 h3 = hs8[(int)sv8[3] * NCHB + c];
        u16x8 h4 = hs8[(int)sv8[4] * NCHB + c];
        u16x8 h5 = hs8[(int)sv8[5] * NCHB + c];
        u16x8 h6 = hs8[(int)sv8[6] * NCHB + c];
        u16x8 h7 = hs8[(int)sv8[7] * NCHB + c];
        ACC(h0); ACC(h1); ACC(h2); ACC(h3);
        ACC(h4); ACC(h5); ACC(h6); ACC(h7);
    }
    #undef ACC

    float sv = rsqrtf((float)(dv + 1));
    u16x8 h0v = FIRST ? own : ((const u16x8*)hs0)[t];
    float r0 = (a0 + bf2f(h0v[0])) * sv;
    float r1 = (a1 + bf2f(h0v[1])) * sv;
    float r2 = (a2 + bf2f(h0v[2])) * sv;
    float r3 = (a3 + bf2f(h0v[3])) * sv;
    float r4 = (a4 + bf2f(h0v[4])) * sv;
    float r5 = (a5 + bf2f(h0v[5])) * sv;
    float r6 = (a6 + bf2f(h0v[6])) * sv;
    float r7 = (a7 + bf2f(h0v[7])) * sv;
    if (LAST) {
        float4* o4 = (float4*)outp;
        o4[(size_t)t * 2]     = make_float4(r0, r1, r2, r3);
        o4[(size_t)t * 2 + 1] = make_float4(r4, r5, r6, r7);
    } else {
        u16x8 o;
        o[0] = f2bf(r0 * sv); o[1] = f2bf(r1 * sv);
        o[2] = f2bf(r2 * sv); o[3] = f2bf(r3 * sv);
        o[4] = f2bf(r4 * sv); o[5] = f2bf(r5 * sv);
        o[6] = f2bf(r6 * sv); o[7] = f2bf(r7 * sv);
        ((u16x8*)outp)[t] = o;
    }
}

// ---------------- launch ----------------

extern "C" void kernel_launch(void* const* d_in, const int* in_sizes, int n_in,
                              void* d_out, int out_size, void* d_ws, size_t ws_size,
                              hipStream_t stream) {
    const int*   src  = (const int*)d_in[0];
    const int*   dst  = (const int*)d_in[1];
    const float* feat = (const float*)d_in[2];
    const int E  = in_sizes[0];
    const int n  = in_sizes[2] / NDF;
    const int nr = E - n;              // random edges; appended self-loops implicit
    float* out = (float*)d_out;

    // workspace carve-up (256B aligned)
    char* p = (char*)d_ws;
    auto take = [&](size_t bytes) {
        char* r = p;
        p += (bytes + 255) & ~size_t(255);
        return r;
    };
    const int NBK = (n + 255) >> 8;    // dst-buckets of 256 nodes
    int* bcount          = (int*)take(256 * 4);
    int* row_ptr         = (int*)take((size_t)n * 4);
    int* rdeg            = (int*)take((size_t)n * 4);
    unsigned int* bucket = (unsigned int*)take((size_t)256 * BCAP * 4);
    unsigned short* csr  = (unsigned short*)take((size_t)256 * BCAP * 2);
    unsigned short* hs0  = (unsigned short*)take((size_t)(n + 1) * NDF * 2);
    unsigned short* hsB  = (unsigned short*)take((size_t)(n + 1) * NDF * 2);
    unsigned short* hsC  = (unsigned short*)take((size_t)(n + 1) * NDF * 2);
    (void)ws_size;

    const int nt = n * NCHB;
    const int bT = (nt + 255) / 256;
    const int bA = (nr + TILE - 1) / TILE;

    // build (3 launches): init -> bucket partition -> fused count/fill/scale
    k_binit <<<1, 256, 0, stream>>>(bcount, hs0, hsB, hsC, n);
    k_passA <<<bA, 512, 0, stream>>>(src, dst, nr, bcount, bucket);
    k_passBC<<<NBK, 512, 0, stream>>>(bcount, bucket, feat, rdeg, row_ptr,
                                      csr, hs0, n);

    // K = 3 propagation rounds (hs0 pristine; rounds 2/3 ping-pong hsB/hsC)
    k_prop<1, 0><<<bT, 256, 0, stream>>>(hs0, hs0, row_ptr, rdeg, csr, hsB, nt);
    k_prop<0, 0><<<bT, 256, 0, stream>>>(hsB, hs0, row_ptr, rdeg, csr, hsC, nt);
    k_prop<0, 1><<<bT, 256, 0, stream>>>(hsC, hs0, row_ptr, rdeg, csr, out, nt);
}

// Round 13
// 105.813 us; speedup vs baseline: 4.6407x; 1.0013x over previous
//
#include <hip/hip_runtime.h>

#define NDF 96            // feature dim
#define NCHB 12           // u16x8 (8-feat, 16B) chunks per bf16 feature row (96/8)
#define BSH 8             // 256 nodes per dst-bucket
#define BCAP 8192         // entries per bucket (u32 bucket slab & padded csr slab)
#define TILE 4096         // edges per passA block

typedef unsigned short u16x8 __attribute__((ext_vector_type(8)));

__device__ __forceinline__ float bf2f(unsigned short u) {
    union { unsigned int i; float f; } x;
    x.i = ((unsigned int)u) << 16;
    return x.f;
}
__device__ __forceinline__ unsigned short f2bf(float f) {
    union { float f; unsigned int i; } x;
    x.f = f;
    unsigned int i = x.i;
    return (unsigned short)((i + 0x7FFFu + ((i >> 16) & 1u)) >> 16);  // RNE
}

// Pass A: partition random edges into dst-buckets of 256 nodes. Per block:
// LDS histogram -> LDS scan -> global per-bucket reservation -> LDS staging
// in bucket-grouped order -> coalesced write of (dst<<16|src) u32 entries.
// (bcount is zeroed by hipMemsetAsync before this launch.)
__global__ void __launch_bounds__(512) k_passA(
        const int* __restrict__ src, const int* __restrict__ dst, int nr,
        int* __restrict__ bcount, unsigned int* __restrict__ bucket) {
    __shared__ unsigned int stage[TILE];
    __shared__ int cnt[256], sstart[256], lcur[256], gbase[256];
    __shared__ int wsum4[4], pref4[4];
    int tid  = threadIdx.x;
    int tile = blockIdx.x * TILE;
    int cnt_e = min(TILE, nr - tile);
    if (tid < 256) cnt[tid] = 0;
    __syncthreads();
    for (int k = tid; k < cnt_e; k += 512)
        atomicAdd(&cnt[dst[tile + k] >> BSH], 1);
    __syncthreads();
    int x = 0, val = 0;
    if (tid < 256) {                  // 256-wide scan: 4 wave-scans + combine
        x = cnt[tid];
        val = x;
        int lane = tid & 63;
        #pragma unroll
        for (int off = 1; off < 64; off <<= 1) {
            int t = __shfl_up(val, off, 64);
            if (lane >= off) val += t;
        }
        if (lane == 63) wsum4[tid >> 6] = val;
    }
    __syncthreads();
    if (tid == 0) {
        int s = 0;
        #pragma unroll
        for (int w = 0; w < 4; ++w) { pref4[w] = s; s += wsum4[w]; }
    }
    __syncthreads();
    if (tid < 256) {
        sstart[tid] = val + pref4[tid >> 6] - x;    // exclusive block-local start
        lcur[tid]   = 0;
        gbase[tid]  = (x > 0) ? atomicAdd(&bcount[tid], x) : 0;
    }
    __syncthreads();
    for (int k = tid; k < cnt_e; k += 512) {
        int d = dst[tile + k];
        int s = src[tile + k];
        int b = d >> BSH;
        int pos = atomicAdd(&lcur[b], 1);
        stage[sstart[b] + pos] = ((unsigned int)d << 16) | (unsigned int)s;
    }
    __syncthreads();
    for (int k = tid; k < cnt_e; k += 512) {        // coalesced write-out
        unsigned int u = stage[k];
        int b = (int)(u >> 24);                     // dst>>8
        bucket[((size_t)b << 13) + gbase[b] + (k - sstart[b])] = u;
    }
}

// Pass BC (fused): per bucket — degree count, padded-length scan, LDS-staged
// CSR fill with sentinel padding, coalesced write-out, feature scaling
// hs0 = bf16(F * d^{-1/2}), and (block 0) zeroing of the three sentinel rows.
__global__ void __launch_bounds__(512) k_passBC(
        const int* __restrict__ bcount, const unsigned int* __restrict__ bucket,
        const float* __restrict__ feat, int* __restrict__ rdeg_g,
        int* __restrict__ row_ptr, unsigned short* __restrict__ csr,
        unsigned short* __restrict__ hs0, unsigned short* __restrict__ hsB,
        unsigned short* __restrict__ hsC, int n) {
    __shared__ int dl[256], cur[256];
    __shared__ int wsum4[4], pref4[4];
    __shared__ int total_s;
    __shared__ unsigned short stg[BCAP];
    int tid = threadIdx.x;
    int b   = blockIdx.x;
    if (b == 0) {                                  // sentinel rows (row n) = 0
        u16x8 z = {0, 0, 0, 0, 0, 0, 0, 0};
        if (tid < NCHB)          ((u16x8*)hs0)[(size_t)n * NCHB + tid]              = z;
        else if (tid < 2 * NCHB) ((u16x8*)hsB)[(size_t)n * NCHB + (tid - NCHB)]     = z;
        else if (tid < 3 * NCHB) ((u16x8*)hsC)[(size_t)n * NCHB + (tid - 2 * NCHB)] = z;
    }
    if (tid < 256) dl[tid] = 0;
    __syncthreads();
    int cb = bcount[b];
    const unsigned int* __restrict__ bp = bucket + ((size_t)b << 13);
    for (int k = tid; k < cb; k += 512)
        atomicAdd(&dl[(bp[k] >> 16) & 255], 1);
    __syncthreads();
    int x = 0, val = 0;
    if (tid < 256) {                  // scan of 8-padded lengths
        x = (dl[tid] + 7) & ~7;
        val = x;
        int lane = tid & 63;
        #pragma unroll
        for (int off = 1; off < 64; off <<= 1) {
            int t = __shfl_up(val, off, 64);
            if (lane >= off) val += t;
        }
        if (lane == 63) wsum4[tid >> 6] = val;
    }
    __syncthreads();
    if (tid == 0) {
        int s = 0;
        #pragma unroll
        for (int w = 0; w < 4; ++w) { pref4[w] = s; s += wsum4[w]; }
        total_s = s;
    }
    __syncthreads();
    if (tid < 256) {
        int off_ex = val + pref4[tid >> 6] - x;     // padded exclusive offset
        cur[tid] = off_ex;
        int node = (b << BSH) + tid;
        if (node < n) {
            rdeg_g[node]  = dl[tid];
            row_ptr[node] = (b << 13) + off_ex;
        }
    }
    __syncthreads();
    int total = total_s;
    for (int k = tid; k < total; k += 512)          // sentinel padding
        stg[k] = (unsigned short)n;
    __syncthreads();
    for (int k = tid; k < cb; k += 512) {           // LDS scatter
        unsigned int u = bp[k];
        int p = atomicAdd(&cur[(u >> 16) & 255], 1);
        stg[p] = (unsigned short)(u & 0xFFFFu);
    }
    __syncthreads();
    unsigned short* __restrict__ cout = csr + ((size_t)b << 13);
    for (int k = tid; k < total; k += 512)          // coalesced write-out
        cout[k] = stg[k];
    // fused feature scaling for this bucket's nodes (dl stable since count)
    const float4* __restrict__ f4 = (const float4*)feat;
    for (int k = tid; k < 256 * NCHB; k += 512) {
        int lv = k / NCHB;
        int c  = k - lv * NCHB;
        int v  = (b << BSH) + lv;
        if (v >= n) break;                          // k monotonic per thread
        float s = rsqrtf((float)(dl[lv] + 1));
        int ci = v * NCHB + c;
        float4 fa = f4[(size_t)ci * 2];
        float4 fb = f4[(size_t)ci * 2 + 1];
        u16x8 o;
        o[0] = f2bf(fa.x * s);
        o[1] = f2bf(fa.y * s);
        o[2] = f2bf(fa.z * s);
        o[3] = f2bf(fa.w * s);
        o[4] = f2bf(fb.x * s);
        o[5] = f2bf(fb.y * s);
        o[6] = f2bf(fb.z * s);
        o[7] = f2bf(fb.w * s);
        ((u16x8*)hs0)[ci] = o;
    }
}

// ---------------- propagation ----------------
// Thread = (node v, chunk c). Rows 8-padded & sentinel-filled: uniform 8-block
// inner loop, one 16B u16x8 csr load per 8 gathers. The NEXT iteration's index
// block is prefetched during the current gathers (software pipeline) so the
// dependent csr-load latency (~200cyc L2) is off the critical path. The +1
// over-read is in-bounds: csr has 256 slabs allocated, only 196 used.
//   h_new = (acc + hs0[v]) * ds,   ds = rsqrt(rdeg+1)
//   FIRST=1: hs==hs0, init term reuses the in-register own row.
//   LAST=0: write bf16(h_new * ds);  LAST=1: write fp32 h_new.
template <int FIRST, int LAST>
__global__ void __launch_bounds__(256) k_prop(
        const unsigned short* __restrict__ hs, const unsigned short* __restrict__ hs0,
        const int* __restrict__ row_ptr, const int* __restrict__ rdeg,
        const unsigned short* __restrict__ csr,
        void* __restrict__ outp, int nt) {
    int t = blockIdx.x * blockDim.x + threadIdx.x;
    if (t >= nt) return;
    int v = t / NCHB;
    int c = t - v * NCHB;
    int beg = row_ptr[v];                       // multiple of 8
    int dv  = rdeg[v];
    int nit = (dv + 7) >> 3;                    // 8-blocks (padded)
    const u16x8* __restrict__ hs8  = (const u16x8*)hs;
    const u16x8* __restrict__ csr8 = (const u16x8*)csr + (beg >> 3);
    u16x8 own = hs8[t];                         // self-loop contribution
    float a0 = bf2f(own[0]), a1 = bf2f(own[1]);
    float a2 = bf2f(own[2]), a3 = bf2f(own[3]);
    float a4 = bf2f(own[4]), a5 = bf2f(own[5]);
    float a6 = bf2f(own[6]), a7 = bf2f(own[7]);

    #define ACC(HV) do { \
        a0 += bf2f((HV)[0]); a1 += bf2f((HV)[1]); \
        a2 += bf2f((HV)[2]); a3 += bf2f((HV)[3]); \
        a4 += bf2f((HV)[4]); a5 += bf2f((HV)[5]); \
        a6 += bf2f((HV)[6]); a7 += bf2f((HV)[7]); } while (0)

    u16x8 sv8 = csr8[0];                        // first index block
    for (int it = 0; it < nit; ++it) {
        u16x8 svn = csr8[it + 1];               // prefetch next (safe over-read)
        u16x8 h0 = hs8[(int)sv8[0] * NCHB + c];
        u16x8 h1 = hs8[(int)sv8[1] * NCHB + c];
        u16x8 h2 = hs8[(int)sv8[2] * NCHB + c];
        u16x8 h3 = hs8[(int)sv8[3] * NCHB + c];
        u16x8 h4 = hs8[(int)sv8[4] * NCHB + c];
        u16x8 h5 = hs8[(int)sv8[5] * NCHB + c];
        u16x8 h6 = hs8[(int)sv8[6] * NCHB + c];
        u16x8 h7 = hs8[(int)sv8[7] * NCHB + c];
        ACC(h0); ACC(h1); ACC(h2); ACC(h3);
        ACC(h4); ACC(h5); ACC(h6); ACC(h7);
        sv8 = svn;
    }
    #undef ACC

    float sv = rsqrtf((float)(dv + 1));
    u16x8 h0v = FIRST ? own : ((const u16x8*)hs0)[t];
    float r0 = (a0 + bf2f(h0v[0])) * sv;
    float r1 = (a1 + bf2f(h0v[1])) * sv;
    float r2 = (a2 + bf2f(h0v[2])) * sv;
    float r3 = (a3 + bf2f(h0v[3])) * sv;
    float r4 = (a4 + bf2f(h0v[4])) * sv;
    float r5 = (a5 + bf2f(h0v[5])) * sv;
    float r6 = (a6 + bf2f(h0v[6])) * sv;
    float r7 = (a7 + bf2f(h0v[7])) * sv;
    if (LAST) {
        float4* o4 = (float4*)outp;
        o4[(size_t)t * 2]     = make_float4(r0, r1, r2, r3);
        o4[(size_t)t * 2 + 1] = make_float4(r4, r5, r6, r7);
    } else {
        u16x8 o;
        o[0] = f2bf(r0 * sv); o[1] = f2bf(r1 * sv);
        o[2] = f2bf(r2 * sv); o[3] = f2bf(r3 * sv);
        o[4] = f2bf(r4 * sv); o[5] = f2bf(r5 * sv);
        o[6] = f2bf(r6 * sv); o[7] = f2bf(r7 * sv);
        ((u16x8*)outp)[t] = o;
    }
}

// ---------------- launch ----------------

extern "C" void kernel_launch(void* const* d_in, const int* in_sizes, int n_in,
                              void* d_out, int out_size, void* d_ws, size_t ws_size,
                              hipStream_t stream) {
    const int*   src  = (const int*)d_in[0];
    const int*   dst  = (const int*)d_in[1];
    const float* feat = (const float*)d_in[2];
    const int E  = in_sizes[0];
    const int n  = in_sizes[2] / NDF;
    const int nr = E - n;              // random edges; appended self-loops implicit
    float* out = (float*)d_out;

    // workspace carve-up (256B aligned)
    char* p = (char*)d_ws;
    auto take = [&](size_t bytes) {
        char* r = p;
        p += (bytes + 255) & ~size_t(255);
        return r;
    };
    const int NBK = (n + 255) >> 8;    // dst-buckets of 256 nodes
    int* bcount          = (int*)take(256 * 4);
    int* row_ptr         = (int*)take((size_t)n * 4);
    int* rdeg            = (int*)take((size_t)n * 4);
    unsigned int* bucket = (unsigned int*)take((size_t)256 * BCAP * 4);
    unsigned short* csr  = (unsigned short*)take((size_t)256 * BCAP * 2);
    unsigned short* hs0  = (unsigned short*)take((size_t)(n + 1) * NDF * 2);
    unsigned short* hsB  = (unsigned short*)take((size_t)(n + 1) * NDF * 2);
    unsigned short* hsC  = (unsigned short*)take((size_t)(n + 1) * NDF * 2);
    (void)ws_size;

    const int nt = n * NCHB;
    const int bT = (nt + 255) / 256;
    const int bA = (nr + TILE - 1) / TILE;

    // build: async memset of bucket counters, then 2 kernels
    hipMemsetAsync(bcount, 0, 256 * 4, stream);
    k_passA <<<bA, 512, 0, stream>>>(src, dst, nr, bcount, bucket);
    k_passBC<<<NBK, 512, 0, stream>>>(bcount, bucket, feat, rdeg, row_ptr,
                                      csr, hs0, hsB, hsC, n);

    // K = 3 propagation rounds (hs0 pristine; rounds 2/3 ping-pong hsB/hsC)
    k_prop<1, 0><<<bT, 256, 0, stream>>>(hs0, hs0, row_ptr, rdeg, csr, hsB, nt);
    k_prop<0, 0><<<bT, 256, 0, stream>>>(hsB, hs0, row_ptr, rdeg, csr, hsC, nt);
    k_prop<0, 1><<<bT, 256, 0, stream>>>(hsC, hs0, row_ptr, rdeg, csr, out, nt);
}